// Round 16
// baseline (485.618 us; speedup 1.0000x reference)
//
#include <hip/hip_runtime.h>
#include <hip/hip_bf16.h>

#define HID 512

typedef __attribute__((ext_vector_type(8))) short bf16x8;
typedef __attribute__((ext_vector_type(4))) float f32x4;

__device__ inline unsigned short f2bf(float x) {
    __hip_bfloat16 b = __float2bfloat16(x);
    return *reinterpret_cast<unsigned short*>(&b);
}
__device__ inline float bf_lo(unsigned int u) { return __uint_as_float(u << 16); }
__device__ inline float bf_hi(unsigned int u) { return __uint_as_float(u & 0xffff0000u); }
__device__ inline unsigned int pk2(float a, float b) {
    return (unsigned)f2bf(a) | ((unsigned)f2bf(b) << 16);
}

#define GLOAD_LDS16(g, l)  __builtin_amdgcn_global_load_lds( \
    (const __attribute__((address_space(1))) void*)(g), \
    (__attribute__((address_space(3))) void*)(l), 16, 0, 0)

// ---------------- degree / CSR build ----------------

__global__ __launch_bounds__(256) void k_deg(const int* __restrict__ ei, int E, int* __restrict__ deg) {
    int e = blockIdx.x * 256 + threadIdx.x;
    if (e < E) atomicAdd(&deg[ei[E + e]], 1);
}

__global__ __launch_bounds__(256) void k_dinv(const int* __restrict__ deg, float* __restrict__ dinv, int N) {
    int n = blockIdx.x * 256 + threadIdx.x;
    if (n < N) {
        int c = deg[n];
        dinv[n] = (c > 0) ? rsqrtf((float)c) : 0.0f;
    }
}

__global__ __launch_bounds__(256) void k_scan1(const int* __restrict__ deg, int N,
                                               int* __restrict__ rowptr, int* __restrict__ bsum) {
    int i = blockIdx.x * 256 + threadIdx.x;
    int v = (i < N) ? deg[i] : 0;
    int lane = threadIdx.x & 63, w = threadIdx.x >> 6;
    int s = v;
    #pragma unroll
    for (int m = 1; m < 64; m <<= 1) { int t = __shfl_up(s, m); if (lane >= m) s += t; }
    __shared__ int wsum[4];
    if (lane == 63) wsum[w] = s;
    __syncthreads();
    #pragma unroll
    for (int j = 0; j < 4; ++j) if (j < w) s += wsum[j];
    if (i < N) rowptr[i + 1] = s;
    if (threadIdx.x == 255) bsum[blockIdx.x] = s;
}

__global__ __launch_bounds__(256) void k_scan2(int* __restrict__ bsum, int nb) {
    int tid = threadIdx.x;
    int v = (tid < nb) ? bsum[tid] : 0;
    int lane = tid & 63, w = tid >> 6;
    int s = v;
    #pragma unroll
    for (int m = 1; m < 64; m <<= 1) { int t = __shfl_up(s, m); if (lane >= m) s += t; }
    __shared__ int wsum[4];
    if (lane == 63) wsum[w] = s;
    __syncthreads();
    #pragma unroll
    for (int j = 0; j < 4; ++j) if (j < w) s += wsum[j];
    if (tid < nb) bsum[tid] = s - v;
}

__global__ __launch_bounds__(256) void k_scan3(const int* __restrict__ deg, const int* __restrict__ bsum,
                                               int N, int* __restrict__ rowptr, int* __restrict__ cursor) {
    int i = blockIdx.x * 256 + threadIdx.x;
    if (i == 0) rowptr[0] = 0;
    if (i < N) {
        int inc = rowptr[i + 1] + bsum[blockIdx.x];
        rowptr[i + 1] = inc;
        cursor[i] = inc - deg[i];
    }
}

__global__ __launch_bounds__(256) void k_fill(const int* __restrict__ ei, int E,
                                              const float* __restrict__ dinv, int* __restrict__ cursor,
                                              int* __restrict__ esrc, float* __restrict__ escale) {
    int e = blockIdx.x * 256 + threadIdx.x;
    if (e < E) {
        int s = ei[e], d = ei[E + e];
        int slot = atomicAdd(&cursor[d], 1);
        esrc[slot] = s;
        escale[slot] = dinv[s];
    }
}

// ---------------- weight prep: transpose + bf16 ----------------

__global__ __launch_bounds__(256) void k_wprep(const float* __restrict__ Wg, const float* __restrict__ Wgate,
                                               unsigned short* __restrict__ WgT, unsigned short* __restrict__ WgateT) {
    int id = blockIdx.x * 256 + threadIdx.x;
    if (id < 3 * 512 * 512) {
        int i = id >> 18, rem = id & 262143;
        int n = rem >> 9, k = rem & 511;
        WgT[id] = f2bf(Wg[((size_t)i * 512 + k) * 512 + n]);
    } else {
        int rem = id - 3 * 512 * 512;
        if (rem < 512 * 1024) {
            int n = rem >> 10, k = rem & 1023;
            WgateT[rem] = f2bf(Wgate[(size_t)k * 512 + n]);
        }
    }
}

// ---------------- h_in (fp32) -> bf16 ----------------

__global__ __launch_bounds__(256) void k_hbf(const float* __restrict__ in, unsigned short* __restrict__ out, int total8) {
    int i = blockIdx.x * 256 + threadIdx.x;
    if (i >= total8) return;
    const float4* p = (const float4*)(in + (size_t)i * 8);
    float4 a = p[0], b = p[1];
    uint4 o;
    o.x = pk2(a.x, a.y);
    o.y = pk2(a.z, a.w);
    o.z = pk2(b.x, b.y);
    o.w = pk2(b.z, b.w);
    *(uint4*)(out + (size_t)i * 8) = o;
}

// ---------------- MFMA GEMM: C[M,512] = A[M,K] @ BT[512,K]^T ----------------
// r15 structure + double-buffered LDS with stage(t+1)-BEFORE-compute(t):
// loads for the next tile fly during the current tile's MFMAs, and the single
// __syncthreads per tile drains them only after a full compute phase.
// MODE 0: write out_bf (xw). MODE 1: gate+blend, hc=A1, hn=A2 -> out_bf (new h bf16).
// MODE 2: gate+blend+tanh+residual (h_orig read as bf16 h0b) -> outp f32.

template<int MODE, int K>
__global__ __launch_bounds__(256, 4) void k_mm(const unsigned short* __restrict__ A1,
                                               const unsigned short* __restrict__ A2,
                                               const unsigned short* __restrict__ BT, int M,
                                               unsigned short* __restrict__ out_bf,
                                               const float* __restrict__ bg,
                                               const unsigned short* __restrict__ h0b,
                                               const float* __restrict__ rw_p,
                                               float* __restrict__ outp) {
    __shared__ char smem[65536];   // 2 x (As 16K + Bs 16K)

    const int tid  = threadIdx.x;
    const int lane = tid & 63;
    const int w    = tid >> 6;       // 0..3
    const int wm   = w >> 1;         // 0..1
    const int wn   = w & 1;          // 0..1

    // sibling-grouping swizzle: panel p -> XCD p%8 (bid%8 round-robin),
    // 4 siblings (n-blocks) consecutive on that XCD; ragged tail linear.
    const int bid = blockIdx.x;
    const int P   = (int)(gridDim.x >> 2);     // m-panels
    const int G4  = (P & ~7) << 2;             // blocks in grouped region
    int p, j;
    if (bid < G4) { int x = bid & 7, q = bid >> 3; j = q & 3; p = x + 8 * (q >> 2); }
    else          { int idx = bid - G4; p = (P & ~7) + (idx >> 2); j = idx & 3; }
    const int bm = p * 128;
    const int bn = j * 128;

    const int lr  = lane >> 3;       // row within 8-row DMA chunk
    const int ls  = lane & 7;        // 16B slot in row
    const int kel = (ls ^ lr) * 8;   // pre-swizzled source k offset

    f32x4 acc[4][4] = {};
    constexpr int NT = K / 64;

    auto stage = [&](int buf, int t) {
        unsigned short* As = (unsigned short*)(smem + buf * 32768);
        unsigned short* Bs = (unsigned short*)(smem + buf * 32768 + 16384);
        const int k0 = t * 64;
        const unsigned short* Asrc = (MODE != 0 && k0 >= 512) ? A2 : A1;
        const int ka = k0 & 511;
        #pragma unroll
        for (int q = 0; q < 4; ++q) {
            int row = w * 32 + q * 8;
            GLOAD_LDS16(Asrc + (size_t)(bm + row + lr) * 512 + ka + kel, As + (size_t)row * 64);
        }
        #pragma unroll
        for (int q = 0; q < 4; ++q) {
            int row = w * 32 + q * 8;
            GLOAD_LDS16(BT + (size_t)(bn + row + lr) * K + k0 + kel, Bs + (size_t)row * 64);
        }
    };
    auto compute = [&](int buf) {
        const char* As_ = smem + buf * 32768;
        const char* Bs_ = As_ + 16384;
        #pragma unroll
        for (int kk = 0; kk < 2; ++kk) {
            const int slot = ((kk * 4 + (lane >> 4)) ^ (lane & 7)) << 4;
            bf16x8 a[4], b[4];
            #pragma unroll
            for (int mi = 0; mi < 4; ++mi) {
                int row = wm * 64 + mi * 16 + (lane & 15);
                a[mi] = *(const bf16x8*)(As_ + row * 128 + slot);
            }
            #pragma unroll
            for (int ni = 0; ni < 4; ++ni) {
                int row = wn * 64 + ni * 16 + (lane & 15);
                b[ni] = *(const bf16x8*)(Bs_ + row * 128 + slot);
            }
            #pragma unroll
            for (int mi = 0; mi < 4; ++mi)
                #pragma unroll
                for (int ni = 0; ni < 4; ++ni)
                    acc[mi][ni] = __builtin_amdgcn_mfma_f32_16x16x32_bf16(a[mi], b[ni], acc[mi][ni], 0, 0, 0);
        }
    };

    // prologue: fill buf0, drain, then overlapped steady state
    stage(0, 0);
    __syncthreads();
    #pragma unroll
    for (int t = 0; t < NT; ++t) {
        if (t + 1 < NT) stage((t + 1) & 1, t + 1);   // next tile flies during compute
        compute(t & 1);
        __syncthreads();   // drains stage(t+1) (covered by compute) + guards buffer reuse
    }

    // ---- coalesced epilogue via per-wave LDS transpose (buf0 region free) ----
    float* cs = (float*)(smem + w * 4352);    // 16 rows x stride 68 f32
    const int wrow = (lane >> 4) * 4;
    const int wcol = lane & 15;
    const int rr = lane >> 2;                 // 0..15
    const int c4 = (lane & 3) * 8;            // 0/8/16/24
    float rwv = (MODE == 2) ? *rw_p : 0.0f;

    #pragma unroll
    for (int mi = 0; mi < 4; ++mi) {
        #pragma unroll
        for (int ni = 0; ni < 4; ++ni)
            #pragma unroll
            for (int jj = 0; jj < 4; ++jj)
                cs[(wrow + jj) * 68 + ni * 16 + wcol] = acc[mi][ni][jj];
        // same-wave LDS write->read; compiler orders via lgkmcnt
        int row = bm + wm * 64 + mi * 16 + rr;
        if (row < M) {
            #pragma unroll 1
            for (int half = 0; half < 2; ++half) {
                int col = bn + wn * 64 + c4 + half * 32;
                size_t base = (size_t)row * 512 + col;
                float4 q0 = *(const float4*)&cs[rr * 68 + c4 + half * 32];
                float4 q1 = *(const float4*)&cs[rr * 68 + c4 + half * 32 + 4];
                if (MODE == 0) {
                    uint4 o0;
                    o0.x = pk2(q0.x, q0.y); o0.y = pk2(q0.z, q0.w);
                    o0.z = pk2(q1.x, q1.y); o0.w = pk2(q1.z, q1.w);
                    *(uint4*)(out_bf + base) = o0;
                } else {
                    uint4 cu = *(const uint4*)(A1 + base);
                    uint4 nu = *(const uint4*)(A2 + base);
                    float4 b0 = *(const float4*)&bg[col];
                    float4 b1 = *(const float4*)&bg[col + 4];
                    float vv[8] = {q0.x, q0.y, q0.z, q0.w, q1.x, q1.y, q1.z, q1.w};
                    float bb[8] = {b0.x, b0.y, b0.z, b0.w, b1.x, b1.y, b1.z, b1.w};
                    float hc[8] = {bf_lo(cu.x), bf_hi(cu.x), bf_lo(cu.y), bf_hi(cu.y),
                                   bf_lo(cu.z), bf_hi(cu.z), bf_lo(cu.w), bf_hi(cu.w)};
                    float hn[8] = {bf_lo(nu.x), bf_hi(nu.x), bf_lo(nu.y), bf_hi(nu.y),
                                   bf_lo(nu.z), bf_hi(nu.z), bf_lo(nu.w), bf_hi(nu.w)};
                    float o[8];
                    #pragma unroll
                    for (int i = 0; i < 8; ++i) {
                        float g = 1.0f / (1.0f + __expf(-(vv[i] + bb[i])));
                        o[i] = g * hn[i] + (1.0f - g) * hc[i];
                    }
                    if (MODE == 1) {
                        uint4 o0;
                        o0.x = pk2(o[0], o[1]); o0.y = pk2(o[2], o[3]);
                        o0.z = pk2(o[4], o[5]); o0.w = pk2(o[6], o[7]);
                        *(uint4*)(out_bf + base) = o0;
                    } else {
                        uint4 hu = *(const uint4*)(h0b + base);   // pristine bf16 h_in
                        float4 r0 = {tanhf(o[0]) + rwv * bf_lo(hu.x),
                                     tanhf(o[1]) + rwv * bf_hi(hu.x),
                                     tanhf(o[2]) + rwv * bf_lo(hu.y),
                                     tanhf(o[3]) + rwv * bf_hi(hu.y)};
                        float4 r1 = {tanhf(o[4]) + rwv * bf_lo(hu.z),
                                     tanhf(o[5]) + rwv * bf_hi(hu.z),
                                     tanhf(o[6]) + rwv * bf_lo(hu.w),
                                     tanhf(o[7]) + rwv * bf_hi(hu.w)};
                        *(float4*)&outp[base]     = r0;
                        *(float4*)&outp[base + 4] = r1;
                    }
                }
            }
        }
    }
}

// ---------------- fused gather + bias + LayerNorm -> bf16 h ----------------

__global__ __launch_bounds__(256) void k_gather(const unsigned short* __restrict__ xw,
                                                const int* __restrict__ rowptr,
                                                const int* __restrict__ esrc, const float* __restrict__ escale,
                                                const float* __restrict__ dinv, const float* __restrict__ bias,
                                                const float* __restrict__ gamma, const float* __restrict__ beta,
                                                unsigned short* __restrict__ outb, int N) {
    int wave = threadIdx.x >> 6, lane = threadIdx.x & 63;
    int n = blockIdx.x * 4 + wave;
    if (n >= N) return;
    int beg = rowptr[n], end = rowptr[n + 1];
    int c0 = lane * 8;
    float acc[8] = {};
    for (int j = beg; j < end; ++j) {
        int s = esrc[j];
        float w = escale[j];
        uint4 u = *(const uint4*)(xw + (size_t)s * HID + c0);
        acc[0] = fmaf(w, bf_lo(u.x), acc[0]); acc[1] = fmaf(w, bf_hi(u.x), acc[1]);
        acc[2] = fmaf(w, bf_lo(u.y), acc[2]); acc[3] = fmaf(w, bf_hi(u.y), acc[3]);
        acc[4] = fmaf(w, bf_lo(u.z), acc[4]); acc[5] = fmaf(w, bf_hi(u.z), acc[5]);
        acc[6] = fmaf(w, bf_lo(u.w), acc[6]); acc[7] = fmaf(w, bf_hi(u.w), acc[7]);
    }
    float dn = dinv[n];
    float4 b0 = *(const float4*)&bias[c0];
    float4 b1 = *(const float4*)&bias[c0 + 4];
    float bb[8] = {b0.x, b0.y, b0.z, b0.w, b1.x, b1.y, b1.z, b1.w};
    float v[8];
    #pragma unroll
    for (int j = 0; j < 8; ++j) v[j] = fmaf(acc[j], dn, bb[j]);
    float s1 = 0.f, s2 = 0.f;
    #pragma unroll
    for (int j = 0; j < 8; ++j) { s1 += v[j]; s2 += v[j] * v[j]; }
    #pragma unroll
    for (int m = 1; m < 64; m <<= 1) { s1 += __shfl_xor(s1, m); s2 += __shfl_xor(s2, m); }
    float mu  = s1 * (1.0f / 512.0f);
    float var = fmaxf(s2 * (1.0f / 512.0f) - mu * mu, 0.0f);
    float r   = rsqrtf(var + 1e-5f);
    float4 g0 = *(const float4*)&gamma[c0];
    float4 g1 = *(const float4*)&gamma[c0 + 4];
    float4 e0 = *(const float4*)&beta[c0];
    float4 e1 = *(const float4*)&beta[c0 + 4];
    float g[8]  = {g0.x, g0.y, g0.z, g0.w, g1.x, g1.y, g1.z, g1.w};
    float bt[8] = {e0.x, e0.y, e0.z, e0.w, e1.x, e1.y, e1.z, e1.w};
    float o[8];
    #pragma unroll
    for (int j = 0; j < 8; ++j) o[j] = (v[j] - mu) * r * g[j] + bt[j];
    uint4 ob;
    ob.x = pk2(o[0], o[1]);
    ob.y = pk2(o[2], o[3]);
    ob.z = pk2(o[4], o[5]);
    ob.w = pk2(o[6], o[7]);
    *(uint4*)(outb + (size_t)n * HID + c0) = ob;
}

// ---------------- launch ----------------

extern "C" void kernel_launch(void* const* d_in, const int* in_sizes, int n_in,
                              void* d_out, int out_size, void* d_ws, size_t ws_size,
                              hipStream_t stream) {
    const float* h_in   = (const float*)d_in[1];
    const int*   ei     = (const int*)d_in[2];
    const float* W_gcn  = (const float*)d_in[3];
    const float* b_gcn  = (const float*)d_in[4];
    const float* ln_g   = (const float*)d_in[5];
    const float* ln_b   = (const float*)d_in[6];
    const float* W_gate = (const float*)d_in[7];
    const float* b_gate = (const float*)d_in[8];
    const float* rw     = (const float*)d_in[9];
    int N = in_sizes[1] / HID;
    int E = in_sizes[2] / 2;
    float* out = (float*)d_out;

    int MB_ = (N + 127) / 128;
    int MP  = MB_ * 128;

    char* ws = (char*)d_ws;
    size_t off = 0;
    auto alloc = [&](size_t bytes) { void* p = ws + off; off += (bytes + 255) & ~(size_t)255; return p; };
    size_t nbh = (size_t)MP * HID * 2;
    unsigned short* xw    = (unsigned short*)alloc(nbh);
    unsigned short* hbf_in= (unsigned short*)alloc(nbh);   // pristine bf16(h_in)
    unsigned short* hbf0  = (unsigned short*)alloc(nbh);
    unsigned short* hbf1  = (unsigned short*)alloc(nbh);
    unsigned short* hbf2  = (unsigned short*)alloc(nbh);
    unsigned short* WgT   = (unsigned short*)alloc((size_t)3 * 512 * 512 * 2);
    unsigned short* WgateT= (unsigned short*)alloc((size_t)512 * 1024 * 2);
    int*   deg    = (int*)  alloc((size_t)N * 4);
    float* dinv   = (float*)alloc((size_t)N * 4);
    int*   rowptr = (int*)  alloc((size_t)(N + 1) * 4);
    int*   cursor = (int*)  alloc((size_t)N * 4);
    int*   bsum   = (int*)  alloc(1024);
    int*   esrc   = (int*)  alloc((size_t)E * 4);
    float* escale = (float*)alloc((size_t)E * 4);

    int NB = (N + 255) / 256;

    // CSR build
    hipMemsetAsync(deg, 0, (size_t)N * 4, stream);
    k_deg  <<<(E + 255) / 256, 256, 0, stream>>>(ei, E, deg);
    k_dinv <<<NB, 256, 0, stream>>>(deg, dinv, N);
    k_scan1<<<NB, 256, 0, stream>>>(deg, N, rowptr, bsum);
    k_scan2<<<1,  256, 0, stream>>>(bsum, NB);
    k_scan3<<<NB, 256, 0, stream>>>(deg, bsum, N, rowptr, cursor);
    k_fill <<<(E + 255) / 256, 256, 0, stream>>>(ei, E, dinv, cursor, esrc, escale);

    // weight prep + h_in -> bf16
    k_wprep<<<(3 * 512 * 512 + 512 * 1024 + 255) / 256, 256, 0, stream>>>(W_gcn, W_gate, WgT, WgateT);
    k_hbf<<<(N * HID / 8 + 255) / 256, 256, 0, stream>>>(h_in, hbf_in, N * HID / 8);

    int NWG = MB_ * 4;
    int NG = (N + 3) / 4;

    // layer 0
    k_mm<0, 512><<<NWG, 256, 0, stream>>>(hbf_in, nullptr, WgT, N, xw,
                                          nullptr, nullptr, nullptr, nullptr);
    k_gather<<<NG, 256, 0, stream>>>(xw, rowptr, esrc, escale, dinv, b_gcn, ln_g, ln_b, hbf1, N);

    // layer 1: gcn -> gather -> fused gate(K=1024): h = g*hn + (1-g)*h -> hbf0
    k_mm<0, 512><<<NWG, 256, 0, stream>>>(hbf1, nullptr, WgT + (size_t)1 * 512 * 512, N, xw,
                                          nullptr, nullptr, nullptr, nullptr);
    k_gather<<<NG, 256, 0, stream>>>(xw, rowptr, esrc, escale, dinv,
                                     b_gcn + 512, ln_g + 512, ln_b + 512, hbf2, N);
    k_mm<1, 1024><<<NWG, 256, 0, stream>>>(hbf1, hbf2, WgateT, N, hbf0,
                                           b_gate, nullptr, nullptr, nullptr);

    // layer 2: gcn -> gather -> fused gate + tanh + residual (bf16 h_orig) -> out
    k_mm<0, 512><<<NWG, 256, 0, stream>>>(hbf0, nullptr, WgT + (size_t)2 * 512 * 512, N, xw,
                                          nullptr, nullptr, nullptr, nullptr);
    k_gather<<<NG, 256, 0, stream>>>(xw, rowptr, esrc, escale, dinv,
                                     b_gcn + 1024, ln_g + 1024, ln_b + 1024, hbf1, N);
    k_mm<2, 1024><<<NWG, 256, 0, stream>>>(hbf0, hbf1, WgateT, N, nullptr,
                                           b_gate, hbf_in, rw, out);
}

// Round 17
// 473.474 us; speedup vs baseline: 1.0257x; 1.0257x over previous
//
#include <hip/hip_runtime.h>
#include <hip/hip_bf16.h>

#define HID 512

typedef __attribute__((ext_vector_type(8))) short bf16x8;
typedef __attribute__((ext_vector_type(4))) float f32x4;

__device__ inline unsigned short f2bf(float x) {
    __hip_bfloat16 b = __float2bfloat16(x);
    return *reinterpret_cast<unsigned short*>(&b);
}
__device__ inline float bf_lo(unsigned int u) { return __uint_as_float(u << 16); }
__device__ inline float bf_hi(unsigned int u) { return __uint_as_float(u & 0xffff0000u); }
__device__ inline unsigned int pk2(float a, float b) {
    return (unsigned)f2bf(a) | ((unsigned)f2bf(b) << 16);
}

#define GLOAD_LDS16(g, l)  __builtin_amdgcn_global_load_lds( \
    (const __attribute__((address_space(1))) void*)(g), \
    (__attribute__((address_space(3))) void*)(l), 16, 0, 0)

// ---------------- degree / CSR build ----------------

__global__ __launch_bounds__(256) void k_deg(const int* __restrict__ ei, int E, int* __restrict__ deg) {
    int e = blockIdx.x * 256 + threadIdx.x;
    if (e < E) atomicAdd(&deg[ei[E + e]], 1);
}

__global__ __launch_bounds__(256) void k_dinv(const int* __restrict__ deg, float* __restrict__ dinv, int N) {
    int n = blockIdx.x * 256 + threadIdx.x;
    if (n < N) {
        int c = deg[n];
        dinv[n] = (c > 0) ? rsqrtf((float)c) : 0.0f;
    }
}

__global__ __launch_bounds__(256) void k_scan1(const int* __restrict__ deg, int N,
                                               int* __restrict__ rowptr, int* __restrict__ bsum) {
    int i = blockIdx.x * 256 + threadIdx.x;
    int v = (i < N) ? deg[i] : 0;
    int lane = threadIdx.x & 63, w = threadIdx.x >> 6;
    int s = v;
    #pragma unroll
    for (int m = 1; m < 64; m <<= 1) { int t = __shfl_up(s, m); if (lane >= m) s += t; }
    __shared__ int wsum[4];
    if (lane == 63) wsum[w] = s;
    __syncthreads();
    #pragma unroll
    for (int j = 0; j < 4; ++j) if (j < w) s += wsum[j];
    if (i < N) rowptr[i + 1] = s;
    if (threadIdx.x == 255) bsum[blockIdx.x] = s;
}

__global__ __launch_bounds__(256) void k_scan2(int* __restrict__ bsum, int nb) {
    int tid = threadIdx.x;
    int v = (tid < nb) ? bsum[tid] : 0;
    int lane = tid & 63, w = tid >> 6;
    int s = v;
    #pragma unroll
    for (int m = 1; m < 64; m <<= 1) { int t = __shfl_up(s, m); if (lane >= m) s += t; }
    __shared__ int wsum[4];
    if (lane == 63) wsum[w] = s;
    __syncthreads();
    #pragma unroll
    for (int j = 0; j < 4; ++j) if (j < w) s += wsum[j];
    if (tid < nb) bsum[tid] = s - v;
}

__global__ __launch_bounds__(256) void k_scan3(const int* __restrict__ deg, const int* __restrict__ bsum,
                                               int N, int* __restrict__ rowptr, int* __restrict__ cursor) {
    int i = blockIdx.x * 256 + threadIdx.x;
    if (i == 0) rowptr[0] = 0;
    if (i < N) {
        int inc = rowptr[i + 1] + bsum[blockIdx.x];
        rowptr[i + 1] = inc;
        cursor[i] = inc - deg[i];
    }
}

__global__ __launch_bounds__(256) void k_fill(const int* __restrict__ ei, int E,
                                              const float* __restrict__ dinv, int* __restrict__ cursor,
                                              int* __restrict__ esrc, float* __restrict__ escale) {
    int e = blockIdx.x * 256 + threadIdx.x;
    if (e < E) {
        int s = ei[e], d = ei[E + e];
        int slot = atomicAdd(&cursor[d], 1);
        esrc[slot] = s;
        escale[slot] = dinv[s];
    }
}

// ---------------- weight prep: transpose + bf16 ----------------

__global__ __launch_bounds__(256) void k_wprep(const float* __restrict__ Wg, const float* __restrict__ Wgate,
                                               unsigned short* __restrict__ WgT, unsigned short* __restrict__ WgateT) {
    int id = blockIdx.x * 256 + threadIdx.x;
    if (id < 3 * 512 * 512) {
        int i = id >> 18, rem = id & 262143;
        int n = rem >> 9, k = rem & 511;
        WgT[id] = f2bf(Wg[((size_t)i * 512 + k) * 512 + n]);
    } else {
        int rem = id - 3 * 512 * 512;
        if (rem < 512 * 1024) {
            int n = rem >> 10, k = rem & 1023;
            WgateT[rem] = f2bf(Wgate[(size_t)k * 512 + n]);
        }
    }
}

// ---------------- h_in (fp32) -> bf16 ----------------

__global__ __launch_bounds__(256) void k_hbf(const float* __restrict__ in, unsigned short* __restrict__ out, int total8) {
    int i = blockIdx.x * 256 + threadIdx.x;
    if (i >= total8) return;
    const float4* p = (const float4*)(in + (size_t)i * 8);
    float4 a = p[0], b = p[1];
    uint4 o;
    o.x = pk2(a.x, a.y);
    o.y = pk2(a.z, a.w);
    o.z = pk2(b.x, b.y);
    o.w = pk2(b.z, b.w);
    *(uint4*)(out + (size_t)i * 8) = o;
}

// ---------------- MFMA GEMM: C[M,512] = A[M,K] @ BT[512,K]^T ----------------
// Proven-best r15 structure: 128x128 tile, BK=64, 4 waves (2x2), single 32KB LDS
// buffer, __syncthreads 2-barrier loop, global_load_lds w/ pre-swizzled source,
// sibling-grouping XCD swizzle, sector-contiguous register-lean epilogue.
// MODE 0: write out_bf (xw). MODE 1: gate+blend, hc=A1, hn=A2 -> out_bf (new h bf16).
// MODE 2: gate+blend+tanh+residual (h_orig read as bf16 h0b) -> outp f32.

template<int MODE, int K>
__global__ __launch_bounds__(256, 4) void k_mm(const unsigned short* __restrict__ A1,
                                               const unsigned short* __restrict__ A2,
                                               const unsigned short* __restrict__ BT, int M,
                                               unsigned short* __restrict__ out_bf,
                                               const float* __restrict__ bg,
                                               const unsigned short* __restrict__ h0b,
                                               const float* __restrict__ rw_p,
                                               float* __restrict__ outp) {
    __shared__ char smem[32768];   // As 16K + Bs 16K, single buffer
    unsigned short* As = (unsigned short*)smem;
    unsigned short* Bs = (unsigned short*)(smem + 16384);

    const int tid  = threadIdx.x;
    const int lane = tid & 63;
    const int w    = tid >> 6;       // 0..3
    const int wm   = w >> 1;         // 0..1
    const int wn   = w & 1;          // 0..1

    // sibling-grouping swizzle: panel p -> XCD p%8 (bid%8 round-robin),
    // 4 siblings (n-blocks) consecutive on that XCD; ragged tail linear.
    const int bid = blockIdx.x;
    const int P   = (int)(gridDim.x >> 2);     // m-panels
    const int G4  = (P & ~7) << 2;             // blocks in grouped region
    int p, j;
    if (bid < G4) { int x = bid & 7, q = bid >> 3; j = q & 3; p = x + 8 * (q >> 2); }
    else          { int idx = bid - G4; p = (P & ~7) + (idx >> 2); j = idx & 3; }
    const int bm = p * 128;
    const int bn = j * 128;

    const int lr  = lane >> 3;       // row within 8-row DMA chunk
    const int ls  = lane & 7;        // 16B slot in row
    const int kel = (ls ^ lr) * 8;   // pre-swizzled source k offset

    f32x4 acc[4][4] = {};
    constexpr int NT = K / 64;

    for (int t = 0; t < NT; ++t) {
        const int k0 = t * 64;
        const unsigned short* Asrc = (MODE != 0 && k0 >= 512) ? A2 : A1;
        const int ka = k0 & 511;
        #pragma unroll
        for (int q = 0; q < 4; ++q) {
            int row = w * 32 + q * 8;
            GLOAD_LDS16(Asrc + (size_t)(bm + row + lr) * 512 + ka + kel, As + (size_t)row * 64);
        }
        #pragma unroll
        for (int q = 0; q < 4; ++q) {
            int row = w * 32 + q * 8;
            GLOAD_LDS16(BT + (size_t)(bn + row + lr) * K + k0 + kel, Bs + (size_t)row * 64);
        }
        __syncthreads();   // compiler-inserted vmcnt drain; cross-block TLP covers
        #pragma unroll
        for (int kk = 0; kk < 2; ++kk) {
            const int slot = ((kk * 4 + (lane >> 4)) ^ (lane & 7)) << 4;
            bf16x8 a[4], b[4];
            #pragma unroll
            for (int mi = 0; mi < 4; ++mi) {
                int row = wm * 64 + mi * 16 + (lane & 15);
                a[mi] = *(const bf16x8*)((const char*)As + row * 128 + slot);
            }
            #pragma unroll
            for (int ni = 0; ni < 4; ++ni) {
                int row = wn * 64 + ni * 16 + (lane & 15);
                b[ni] = *(const bf16x8*)((const char*)Bs + row * 128 + slot);
            }
            #pragma unroll
            for (int mi = 0; mi < 4; ++mi)
                #pragma unroll
                for (int ni = 0; ni < 4; ++ni)
                    acc[mi][ni] = __builtin_amdgcn_mfma_f32_16x16x32_bf16(a[mi], b[ni], acc[mi][ni], 0, 0, 0);
        }
        __syncthreads();
    }

    // ---- coalesced epilogue via per-wave LDS transpose ----
    // Readback: rr = lane>>2 (row), c4 = (lane&3)*8 cols; chunk = half*32.
    // 4-lane row-groups cover contiguous 64B (bf16) / 128B (f32) per store.
    float* cs = (float*)(smem + w * 4352);    // 16 rows x stride 68 f32
    const int wrow = (lane >> 4) * 4;
    const int wcol = lane & 15;
    const int rr = lane >> 2;                 // 0..15
    const int c4 = (lane & 3) * 8;            // 0/8/16/24
    float rwv = (MODE == 2) ? *rw_p : 0.0f;

    #pragma unroll
    for (int mi = 0; mi < 4; ++mi) {
        #pragma unroll
        for (int ni = 0; ni < 4; ++ni)
            #pragma unroll
            for (int jj = 0; jj < 4; ++jj)
                cs[(wrow + jj) * 68 + ni * 16 + wcol] = acc[mi][ni][jj];
        // same-wave LDS write->read; compiler orders via lgkmcnt
        int row = bm + wm * 64 + mi * 16 + rr;
        if (row < M) {
            #pragma unroll 1
            for (int half = 0; half < 2; ++half) {
                int col = bn + wn * 64 + c4 + half * 32;
                size_t base = (size_t)row * 512 + col;
                float4 q0 = *(const float4*)&cs[rr * 68 + c4 + half * 32];
                float4 q1 = *(const float4*)&cs[rr * 68 + c4 + half * 32 + 4];
                if (MODE == 0) {
                    uint4 o0;
                    o0.x = pk2(q0.x, q0.y); o0.y = pk2(q0.z, q0.w);
                    o0.z = pk2(q1.x, q1.y); o0.w = pk2(q1.z, q1.w);
                    *(uint4*)(out_bf + base) = o0;
                } else {
                    uint4 cu = *(const uint4*)(A1 + base);
                    uint4 nu = *(const uint4*)(A2 + base);
                    float4 b0 = *(const float4*)&bg[col];
                    float4 b1 = *(const float4*)&bg[col + 4];
                    float vv[8] = {q0.x, q0.y, q0.z, q0.w, q1.x, q1.y, q1.z, q1.w};
                    float bb[8] = {b0.x, b0.y, b0.z, b0.w, b1.x, b1.y, b1.z, b1.w};
                    float hc[8] = {bf_lo(cu.x), bf_hi(cu.x), bf_lo(cu.y), bf_hi(cu.y),
                                   bf_lo(cu.z), bf_hi(cu.z), bf_lo(cu.w), bf_hi(cu.w)};
                    float hn[8] = {bf_lo(nu.x), bf_hi(nu.x), bf_lo(nu.y), bf_hi(nu.y),
                                   bf_lo(nu.z), bf_hi(nu.z), bf_lo(nu.w), bf_hi(nu.w)};
                    float o[8];
                    #pragma unroll
                    for (int i = 0; i < 8; ++i) {
                        float g = 1.0f / (1.0f + __expf(-(vv[i] + bb[i])));
                        o[i] = g * hn[i] + (1.0f - g) * hc[i];
                    }
                    if (MODE == 1) {
                        uint4 o0;
                        o0.x = pk2(o[0], o[1]); o0.y = pk2(o[2], o[3]);
                        o0.z = pk2(o[4], o[5]); o0.w = pk2(o[6], o[7]);
                        *(uint4*)(out_bf + base) = o0;
                    } else {
                        uint4 hu = *(const uint4*)(h0b + base);   // pristine bf16 h_in
                        float4 r0 = {tanhf(o[0]) + rwv * bf_lo(hu.x),
                                     tanhf(o[1]) + rwv * bf_hi(hu.x),
                                     tanhf(o[2]) + rwv * bf_lo(hu.y),
                                     tanhf(o[3]) + rwv * bf_hi(hu.y)};
                        float4 r1 = {tanhf(o[4]) + rwv * bf_lo(hu.z),
                                     tanhf(o[5]) + rwv * bf_hi(hu.z),
                                     tanhf(o[6]) + rwv * bf_lo(hu.w),
                                     tanhf(o[7]) + rwv * bf_hi(hu.w)};
                        *(float4*)&outp[base]     = r0;
                        *(float4*)&outp[base + 4] = r1;
                    }
                }
            }
        }
    }
}

// ---------------- fused gather + bias + LayerNorm -> bf16 h ----------------

__global__ __launch_bounds__(256) void k_gather(const unsigned short* __restrict__ xw,
                                                const int* __restrict__ rowptr,
                                                const int* __restrict__ esrc, const float* __restrict__ escale,
                                                const float* __restrict__ dinv, const float* __restrict__ bias,
                                                const float* __restrict__ gamma, const float* __restrict__ beta,
                                                unsigned short* __restrict__ outb, int N) {
    int wave = threadIdx.x >> 6, lane = threadIdx.x & 63;
    int n = blockIdx.x * 4 + wave;
    if (n >= N) return;
    int beg = rowptr[n], end = rowptr[n + 1];
    int c0 = lane * 8;
    float acc[8] = {};
    for (int j = beg; j < end; ++j) {
        int s = esrc[j];
        float w = escale[j];
        uint4 u = *(const uint4*)(xw + (size_t)s * HID + c0);
        acc[0] = fmaf(w, bf_lo(u.x), acc[0]); acc[1] = fmaf(w, bf_hi(u.x), acc[1]);
        acc[2] = fmaf(w, bf_lo(u.y), acc[2]); acc[3] = fmaf(w, bf_hi(u.y), acc[3]);
        acc[4] = fmaf(w, bf_lo(u.z), acc[4]); acc[5] = fmaf(w, bf_hi(u.z), acc[5]);
        acc[6] = fmaf(w, bf_lo(u.w), acc[6]); acc[7] = fmaf(w, bf_hi(u.w), acc[7]);
    }
    float dn = dinv[n];
    float4 b0 = *(const float4*)&bias[c0];
    float4 b1 = *(const float4*)&bias[c0 + 4];
    float bb[8] = {b0.x, b0.y, b0.z, b0.w, b1.x, b1.y, b1.z, b1.w};
    float v[8];
    #pragma unroll
    for (int j = 0; j < 8; ++j) v[j] = fmaf(acc[j], dn, bb[j]);
    float s1 = 0.f, s2 = 0.f;
    #pragma unroll
    for (int j = 0; j < 8; ++j) { s1 += v[j]; s2 += v[j] * v[j]; }
    #pragma unroll
    for (int m = 1; m < 64; m <<= 1) { s1 += __shfl_xor(s1, m); s2 += __shfl_xor(s2, m); }
    float mu  = s1 * (1.0f / 512.0f);
    float var = fmaxf(s2 * (1.0f / 512.0f) - mu * mu, 0.0f);
    float r   = rsqrtf(var + 1e-5f);
    float4 g0 = *(const float4*)&gamma[c0];
    float4 g1 = *(const float4*)&gamma[c0 + 4];
    float4 e0 = *(const float4*)&beta[c0];
    float4 e1 = *(const float4*)&beta[c0 + 4];
    float g[8]  = {g0.x, g0.y, g0.z, g0.w, g1.x, g1.y, g1.z, g1.w};
    float bt[8] = {e0.x, e0.y, e0.z, e0.w, e1.x, e1.y, e1.z, e1.w};
    float o[8];
    #pragma unroll
    for (int j = 0; j < 8; ++j) o[j] = (v[j] - mu) * r * g[j] + bt[j];
    uint4 ob;
    ob.x = pk2(o[0], o[1]);
    ob.y = pk2(o[2], o[3]);
    ob.z = pk2(o[4], o[5]);
    ob.w = pk2(o[6], o[7]);
    *(uint4*)(outb + (size_t)n * HID + c0) = ob;
}

// ---------------- launch ----------------

extern "C" void kernel_launch(void* const* d_in, const int* in_sizes, int n_in,
                              void* d_out, int out_size, void* d_ws, size_t ws_size,
                              hipStream_t stream) {
    const float* h_in   = (const float*)d_in[1];
    const int*   ei     = (const int*)d_in[2];
    const float* W_gcn  = (const float*)d_in[3];
    const float* b_gcn  = (const float*)d_in[4];
    const float* ln_g   = (const float*)d_in[5];
    const float* ln_b   = (const float*)d_in[6];
    const float* W_gate = (const float*)d_in[7];
    const float* b_gate = (const float*)d_in[8];
    const float* rw     = (const float*)d_in[9];
    int N = in_sizes[1] / HID;
    int E = in_sizes[2] / 2;
    float* out = (float*)d_out;

    int MB_ = (N + 127) / 128;
    int MP  = MB_ * 128;

    char* ws = (char*)d_ws;
    size_t off = 0;
    auto alloc = [&](size_t bytes) { void* p = ws + off; off += (bytes + 255) & ~(size_t)255; return p; };
    size_t nbh = (size_t)MP * HID * 2;
    unsigned short* xw    = (unsigned short*)alloc(nbh);
    unsigned short* hbf_in= (unsigned short*)alloc(nbh);   // pristine bf16(h_in)
    unsigned short* hbf0  = (unsigned short*)alloc(nbh);
    unsigned short* hbf1  = (unsigned short*)alloc(nbh);
    unsigned short* hbf2  = (unsigned short*)alloc(nbh);
    unsigned short* WgT   = (unsigned short*)alloc((size_t)3 * 512 * 512 * 2);
    unsigned short* WgateT= (unsigned short*)alloc((size_t)512 * 1024 * 2);
    int*   deg    = (int*)  alloc((size_t)N * 4);
    float* dinv   = (float*)alloc((size_t)N * 4);
    int*   rowptr = (int*)  alloc((size_t)(N + 1) * 4);
    int*   cursor = (int*)  alloc((size_t)N * 4);
    int*   bsum   = (int*)  alloc(1024);
    int*   esrc   = (int*)  alloc((size_t)E * 4);
    float* escale = (float*)alloc((size_t)E * 4);

    int NB = (N + 255) / 256;

    // CSR build
    hipMemsetAsync(deg, 0, (size_t)N * 4, stream);
    k_deg  <<<(E + 255) / 256, 256, 0, stream>>>(ei, E, deg);
    k_dinv <<<NB, 256, 0, stream>>>(deg, dinv, N);
    k_scan1<<<NB, 256, 0, stream>>>(deg, N, rowptr, bsum);
    k_scan2<<<1,  256, 0, stream>>>(bsum, NB);
    k_scan3<<<NB, 256, 0, stream>>>(deg, bsum, N, rowptr, cursor);
    k_fill <<<(E + 255) / 256, 256, 0, stream>>>(ei, E, dinv, cursor, esrc, escale);

    // weight prep + h_in -> bf16
    k_wprep<<<(3 * 512 * 512 + 512 * 1024 + 255) / 256, 256, 0, stream>>>(W_gcn, W_gate, WgT, WgateT);
    k_hbf<<<(N * HID / 8 + 255) / 256, 256, 0, stream>>>(h_in, hbf_in, N * HID / 8);

    int NWG = MB_ * 4;
    int NG = (N + 3) / 4;

    // layer 0
    k_mm<0, 512><<<NWG, 256, 0, stream>>>(hbf_in, nullptr, WgT, N, xw,
                                          nullptr, nullptr, nullptr, nullptr);
    k_gather<<<NG, 256, 0, stream>>>(xw, rowptr, esrc, escale, dinv, b_gcn, ln_g, ln_b, hbf1, N);

    // layer 1: gcn -> gather -> fused gate(K=1024): h = g*hn + (1-g)*h -> hbf0
    k_mm<0, 512><<<NWG, 256, 0, stream>>>(hbf1, nullptr, WgT + (size_t)1 * 512 * 512, N, xw,
                                          nullptr, nullptr, nullptr, nullptr);
    k_gather<<<NG, 256, 0, stream>>>(xw, rowptr, esrc, escale, dinv,
                                     b_gcn + 512, ln_g + 512, ln_b + 512, hbf2, N);
    k_mm<1, 1024><<<NWG, 256, 0, stream>>>(hbf1, hbf2, WgateT, N, hbf0,
                                           b_gate, nullptr, nullptr, nullptr);

    // layer 2: gcn -> gather -> fused gate + tanh + residual (bf16 h_orig) -> out
    k_mm<0, 512><<<NWG, 256, 0, stream>>>(hbf0, nullptr, WgT + (size_t)2 * 512 * 512, N, xw,
                                          nullptr, nullptr, nullptr, nullptr);
    k_gather<<<NG, 256, 0, stream>>>(xw, rowptr, esrc, escale, dinv,
                                     b_gcn + 1024, ln_g + 1024, ln_b + 1024, hbf1, N);
    k_mm<2, 1024><<<NWG, 256, 0, stream>>>(hbf0, hbf1, WgateT, N, nullptr,
                                           b_gate, hbf_in, rw, out);
}